// Round 1
// baseline (373.230 us; speedup 1.0000x reference)
//
#include <hip/hip_runtime.h>
#include <hip/hip_fp16.h>

// Problem constants (fixed by setup_inputs): B=1, KVH=8, D=128, S=8192
#define HH 8
#define DD 128
#define SS 8192

// ---------------- attn mask fill: out[r][c] = (c>r ? -128 : 0) * mask ----------------
// 8192x8192 fp32, written as float4 (2048 float4 per row). Pure store kernel.
__global__ __launch_bounds__(256) void attn_kernel(const int* __restrict__ maskp,
                                                   float* __restrict__ out) {
    const float hi = (float)(-128 * (*maskp));
    int idx = blockIdx.x * 256 + threadIdx.x;   // float4 index, 0 .. 8192*2048-1
    int r  = idx >> 11;                          // row
    int c  = (idx & 2047) << 2;                  // first col of this float4
    float4 v;
    v.x = (c + 0 > r) ? hi : 0.0f;
    v.y = (c + 1 > r) ? hi : 0.0f;
    v.z = (c + 2 > r) ? hi : 0.0f;
    v.w = (c + 3 > r) ? hi : 0.0f;
    ((float4*)out)[idx] = v;
}

// ---------------- keys: layout (H, D, S), quantize over D (stride S) ----------------
// Block = 256 threads covering one (h, 64-wide s-tile): sl = tid&63 (s), td = tid>>6 (d-group).
// Lanes walk s fastest -> contiguous 256B per wave per load/store. Data cached in 32 VGPRs.
__global__ __launch_bounds__(256) void keys_kernel(const float* __restrict__ keys,
                                                   float* __restrict__ kp,
                                                   float* __restrict__ ks,
                                                   float* __restrict__ kb) {
    const int h  = blockIdx.x >> 7;          // 128 s-tiles per head
    const int s0 = (blockIdx.x & 127) << 6;  // s-tile base
    const int sl = threadIdx.x & 63;
    const int td = threadIdx.x >> 6;         // 0..3, each owns 32 d values

    const float* base = keys + (size_t)h * DD * SS + s0 + sl;
    float val[32];
    float mn = 3.0e38f, mx = -3.0e38f;
#pragma unroll
    for (int j = 0; j < 32; ++j) {
        float v = base[(size_t)(td * 32 + j) * SS];
        val[j] = v;
        mn = fminf(mn, v);
        mx = fmaxf(mx, v);
    }

    __shared__ float smin[4][64], smax[4][64], sscale[64], sbias[64];
    smin[td][sl] = mn;
    smax[td][sl] = mx;
    __syncthreads();
    if (td == 0) {
        float m0 = fminf(fminf(smin[0][sl], smin[1][sl]), fminf(smin[2][sl], smin[3][sl]));
        float M0 = fmaxf(fmaxf(smax[0][sl], smax[1][sl]), fmaxf(smax[2][sl], smax[3][sl]));
        float scale = (M0 - m0) * (1.0f / 255.0f);  // fp32, matches (max-min)*(1/QMAX)
        sscale[sl] = scale;
        sbias[sl]  = m0;
        int o = h * SS + s0 + sl;                    // k_scale/k_bias flat [h][s]
        ks[o] = __half2float(__float2half(scale));   // astype(f16) round-trip, RNE
        kb[o] = __half2float(__float2half(m0));
    }
    __syncthreads();
    const float scale = sscale[sl];
    const float bias  = sbias[sl];
    float* ob = kp + (size_t)h * DD * SS + s0 + sl;
#pragma unroll
    for (int j = 0; j < 32; ++j) {
        // packed uses the fp32 scale (astype happens only on returned scale/bias)
        ob[(size_t)(td * 32 + j) * SS] = rintf((val[j] - bias) / scale);
    }
}

// ---------------- values: layout (H, S, D), quantize over contiguous D=128 ----------------
// 32 lanes per row, one float4 each (512B contiguous per 32-lane group). Butterfly
// __shfl_xor (offsets 1..16) stays within each 32-lane group on wave64.
__global__ __launch_bounds__(256) void vals_kernel(const float* __restrict__ vals,
                                                   float* __restrict__ vp,
                                                   float* __restrict__ vs,
                                                   float* __restrict__ vb) {
    const int d4 = threadIdx.x & 31;          // float4 index within row
    const int rr = threadIdx.x >> 5;          // 0..7 rows per block
    const int R  = blockIdx.x * 8 + rr;       // global row: R = h*8192 + s

    const float4 v = ((const float4*)vals)[R * 32 + d4];
    float mn = fminf(fminf(v.x, v.y), fminf(v.z, v.w));
    float mx = fmaxf(fmaxf(v.x, v.y), fmaxf(v.z, v.w));
#pragma unroll
    for (int off = 16; off >= 1; off >>= 1) {
        mn = fminf(mn, __shfl_xor(mn, off));
        mx = fmaxf(mx, __shfl_xor(mx, off));
    }
    const float scale = (mx - mn) * (1.0f / 255.0f);
    if (d4 == 0) {
        // v_scale swapaxes(-1,-2) is a no-op on flat memory: both flat [h][s] = [R]
        vs[R] = __half2float(__float2half(scale));
        vb[R] = __half2float(__float2half(mn));
    }
    float4 o;
    o.x = rintf((v.x - mn) / scale);
    o.y = rintf((v.y - mn) / scale);
    o.z = rintf((v.z - mn) / scale);
    o.w = rintf((v.w - mn) / scale);
    ((float4*)vp)[R * 32 + d4] = o;
}

extern "C" void kernel_launch(void* const* d_in, const int* in_sizes, int n_in,
                              void* d_out, int out_size, void* d_ws, size_t ws_size,
                              hipStream_t stream) {
    const float* keys  = (const float*)d_in[0];
    const float* vals  = (const float*)d_in[1];
    const int*   maskp = (const int*)d_in[2];
    // d_in[3] = ids_len, d_in[4] = kv_seq_len — fixed at 8192 (they define output shapes)

    float* out  = (float*)d_out;
    float* attn = out;                       // 8192*8192      = 67108864
    float* kp   = attn + 67108864;           // 8*128*8192     =  8388608
    float* ks   = kp   + 8388608;            // 8*8192         =    65536
    float* kb   = ks   + 65536;              //                     65536
    float* vp   = kb   + 65536;              //                   8388608
    float* vs   = vp   + 8388608;            //                     65536
    float* vb   = vs   + 65536;              //                     65536

    attn_kernel<<<dim3(SS * (SS / 4) / 256), dim3(256), 0, stream>>>(maskp, attn);
    keys_kernel<<<dim3(HH * (SS / 64)), dim3(256), 0, stream>>>(keys, kp, ks, kb);
    vals_kernel<<<dim3(HH * SS / 8), dim3(256), 0, stream>>>(vals, vp, vs, vb);
}